// Round 4
// baseline (479.576 us; speedup 1.0000x reference)
//
#include <hip/hip_runtime.h>
#include <hip/hip_bf16.h>
#include <stdint.h>

#define S_N   150000
#define DIM   512
#define NUSE  100
#define NPAD  112            // 7 tiles of 16
#define TALF  0.07f
#define BS    128            // s rows per block
#define NBLK  ((S_N + BS - 1) / BS)   // 1172; last block shifted to [S_N-128, S_N)
#define NCHUNK (DIM / 32)    // 16 chunks of 32 k

using short8 = __attribute__((ext_vector_type(8))) short;
using f32x4  = __attribute__((ext_vector_type(4))) float;

__device__ __forceinline__ short f2bf(float f) {
    union { float f; unsigned u; } x; x.f = f;
    unsigned r = x.u + 0x7FFF + ((x.u >> 16) & 1);   // RNE
    return (short)(r >> 16);
}

// ---- P: fused prep (one launch). Per block b (28 blocks x 256):
//   * all threads: pack one short8 of fea into B-fragment order
//   * wave (b*4+w) < 112: fea row norm; < 100: fp32 positive logit
//   * block 0: zero gsum + completion counter
__global__ void prep_all(const float* __restrict__ attr, const float* __restrict__ fea,
                         const int* __restrict__ label,
                         short8* __restrict__ Bws, float* __restrict__ invf_tal,
                         float* __restrict__ expos, float* __restrict__ gsum,
                         int* __restrict__ cnt) {
    int tid = threadIdx.x;
    int idx = blockIdx.x * 256 + tid;                // 0..7167 exactly (28 blocks)
    if (blockIdx.x == 0) {
        if (tid < NPAD) gsum[tid] = 0.f;
        if (tid == NPAD) *cnt = 0;
    }
    {   // B-pack: Bws[(c*7+tn)*64 + lane] covers fea[n=tn*16+l16][c*32+q*8 .. +8]
        int c    = idx / 448;
        int r    = idx % 448;
        int tn   = r / 64;
        int lane = r % 64;
        int n     = tn * 16 + (lane & 15);
        int dbase = c * 32 + ((lane >> 4) & 3) * 8;
        const float* fp = fea + n * DIM + dbase;
        short8 o;
#pragma unroll
        for (int j = 0; j < 8; ++j) o[j] = f2bf(fp[j]);
        Bws[idx] = o;
    }
    int wv   = blockIdx.x * 4 + (tid >> 6);          // one wave per n
    int lane = tid & 63;
    if (wv >= NPAD) return;
    const float* f = fea + wv * DIM;
    float ss = 0.f;
#pragma unroll
    for (int j = 0; j < 8; ++j) { float v = f[lane * 8 + j]; ss += v * v; }
    for (int o = 1; o < 64; o <<= 1) ss += __shfl_xor(ss, o);
    if (lane == 0) invf_tal[wv] = rsqrtf(ss) * (1.0f / TALF);
    if (wv < NUSE) {
        int lab = label[wv];
        float dt = 0.f, aq = 0.f;
#pragma unroll
        for (int j = 0; j < 8; ++j) {
            int d = j * 64 + lane;
            float a  = attr[(size_t)d * S_N + lab];
            float fe = f[d];
            dt += a * fe; aq += a * a;
        }
        for (int o = 1; o < 64; o <<= 1) { dt += __shfl_xor(dt, o); aq += __shfl_xor(aq, o); }
        if (lane == 0) expos[wv] = dt * rsqrtf(aq) * rsqrtf(ss) * (1.0f / TALF);
    }
}

// Async global->LDS, 16B per lane. gptr is per-lane (gather); lptr must be
// wave-uniform base (HW writes lane i at base + i*16).
__device__ __forceinline__ void gl2lds16(const float* gptr, char* lptr) {
    __builtin_amdgcn_global_load_lds(
        (const __attribute__((address_space(1))) unsigned*)(uintptr_t)gptr,
        (__attribute__((address_space(3))) unsigned*)(uintptr_t)lptr,
        16, 0, 0);
}

// ---- Main: stage attr chunks to LDS (double-buffered), MFMA vs packed fea,
// fused column-norm + exp partial sums; LAST finishing block computes the loss
// (device-scope atomics = coherence point, safe across XCDs). ----
__global__ __launch_bounds__(256, 3)
void main_gemm(const float* __restrict__ A, const short8* __restrict__ Bws,
               const float* __restrict__ invf_tal, const float* __restrict__ expos,
               float* __restrict__ gsum, int* __restrict__ cnt,
               float* __restrict__ out) {
    __shared__ float buf[2][32][BS];   // 2 x 16 KB chunk buffers
    __shared__ float psum[4][NPAD];
    __shared__ int lastflag;

    const int tid  = threadIdx.x;
    const int w    = tid >> 6, lane = tid & 63;
    const int q    = lane >> 4, l16 = lane & 15;

    // tail block shifts window so all staging addresses are in-bounds;
    // rows < minr are owned by the previous block and masked in the epilogue.
    const bool tail = (blockIdx.x == NBLK - 1);
    const int s_base = tail ? (S_N - BS) : blockIdx.x * BS;
    const int minr   = tail ? ((NBLK - 1) * BS - (S_N - BS)) : 0;   // 16 or 0

    // staging source: thread t covers k_local = i*8 + (t>>5), s = s_base + (t&31)*4
    const float* gsrc = A + (size_t)(tid >> 5) * S_N + s_base + (tid & 31) * 4;
    // staging dest (wave-uniform): byte offset i*4096 + w*1024 within buf[pc]
    char* lds_w0 = (char*)&buf[0][0][0] + w * 1024;
    char* lds_w1 = (char*)&buf[1][0][0] + w * 1024;

    f32x4 acc[2][7];
#pragma unroll
    for (int mt = 0; mt < 2; ++mt)
#pragma unroll
        for (int tn = 0; tn < 7; ++tn) acc[mt][tn] = f32x4{0.f, 0.f, 0.f, 0.f};

    float ss0 = 0.f, ss1 = 0.f;       // fp32 column sumsq (this lane's k-subset)
    const short8* bp = Bws + lane;

    // stage chunk 0 into buf[0]
#pragma unroll
    for (int i = 0; i < 4; ++i)
        gl2lds16(gsrc + (size_t)i * 8 * S_N, lds_w0 + i * 4096);

    for (int c = 0; c < NCHUNK; ++c) {
        const int pc = c & 1;
        // barrier: (a) drains vmcnt -> chunk c staging complete,
        //          (b) all waves done reading buf[1-pc] from chunk c-1.
        __syncthreads();
        if (c + 1 < NCHUNK) {          // prefetch chunk c+1 into the other buffer;
            const float* gn = gsrc + (size_t)(c + 1) * 32 * S_N;
            char* ldsn = ((c + 1) & 1) ? lds_w1 : lds_w0;
#pragma unroll
            for (int i = 0; i < 4; ++i)
                gl2lds16(gn + (size_t)i * 8 * S_N, ldsn + i * 4096);
        }                              // it has the whole chunk-c compute to land.

        short8 bfr[7];                 // B frags: L2-hot (112 KB dataset)
#pragma unroll
        for (int tn = 0; tn < 7; ++tn) bfr[tn] = bp[(c * 7 + tn) * 64];

        short8 af0, af1;
#pragma unroll
        for (int j = 0; j < 8; ++j) {  // A frags from LDS: lane (q,l16) <- A[k=q*8+j][s]
            float x0 = buf[pc][q * 8 + j][w * 32 + l16];
            float x1 = buf[pc][q * 8 + j][w * 32 + l16 + 16];
            ss0 += x0 * x0; ss1 += x1 * x1;
            af0[j] = f2bf(x0); af1[j] = f2bf(x1);
        }
#pragma unroll
        for (int tn = 0; tn < 7; ++tn) {
            acc[0][tn] = __builtin_amdgcn_mfma_f32_16x16x32_bf16(af0, bfr[tn], acc[0][tn], 0, 0, 0);
            acc[1][tn] = __builtin_amdgcn_mfma_f32_16x16x32_bf16(af1, bfr[tn], acc[1][tn], 0, 0, 0);
        }
    }

    // full column sumsq: k-subsets live across the 4 quads
    ss0 += __shfl_xor(ss0, 16); ss0 += __shfl_xor(ss0, 32);
    ss1 += __shfl_xor(ss1, 16); ss1 += __shfl_xor(ss1, 32);
    float inva0 = rsqrtf(ss0);         // belongs to local row w*32 + l16
    float inva1 = rsqrtf(ss1);         // belongs to local row w*32 + l16 + 16
    // redistribute to C-layout rows (row_in_tile = q*4 + reg)
    float ir0[4], ir1[4];
#pragma unroll
    for (int reg = 0; reg < 4; ++reg) {
        ir0[reg] = __shfl(inva0, q * 4 + reg);
        ir1[reg] = __shfl(inva1, q * 4 + reg);
    }
    float invf_l[7];
#pragma unroll
    for (int tn = 0; tn < 7; ++tn) invf_l[tn] = invf_tal[tn * 16 + l16];

    const float M = 1.0f / TALF;
    const int rloc = w * 32 + q * 4;   // local row base, mt=0 (mt=1: +16)
#pragma unroll
    for (int tn = 0; tn < 7; ++tn) {
        float sacc = 0.f;
#pragma unroll
        for (int reg = 0; reg < 4; ++reg) {
            bool rv0 = (rloc + reg) >= minr;
            bool rv1 = (rloc + 16 + reg) >= minr;
            float ex0 = acc[0][tn][reg] * ir0[reg] * invf_l[tn];
            float ex1 = acc[1][tn][reg] * ir1[reg] * invf_l[tn];
            sacc += rv0 ? __expf(ex0 - M) : 0.f;
            sacc += rv1 ? __expf(ex1 - M) : 0.f;
        }
        sacc += __shfl_xor(sacc, 16);
        sacc += __shfl_xor(sacc, 32);
        if (lane < 16) psum[w][tn * 16 + lane] = sacc;
    }
    __syncthreads();
    if (tid < NPAD) {
        float t = psum[0][tid] + psum[1][tid] + psum[2][tid] + psum[3][tid];
        atomicAdd(&gsum[tid], t);
    }

    // ---- fused finalize: last block to finish computes the loss ----
    // __syncthreads drains this block's gsum atomics (vmcnt(0) before s_barrier),
    // so they are at the L2 coherence point before the counter bump.
    __syncthreads();
    if (tid == 0) {
        __threadfence();
        int old = atomicAdd(cnt, 1);
        lastflag = (old == NBLK - 1) ? 1 : 0;
    }
    __syncthreads();
    if (lastflag) {
        float* r = &psum[0][0];        // reuse 448 floats of LDS
        float v = 0.f;
        if (tid < NUSE) {
            float g = atomicAdd(&gsum[tid], 0.0f);   // device-scope read (XCD-safe)
            v = (M + logf(g)) - expos[tid];
        }
        r[tid] = v;
        __syncthreads();
        for (int s = 128; s > 0; s >>= 1) {
            if (tid < s) r[tid] += r[tid + s];
            __syncthreads();
        }
        if (tid == 0) out[0] = r[0] * (1.0f / NUSE);
    }
}

extern "C" void kernel_launch(void* const* d_in, const int* in_sizes, int n_in,
                              void* d_out, int out_size, void* d_ws, size_t ws_size,
                              hipStream_t stream) {
    const float* attr  = (const float*)d_in[0];   // (512, 150000)
    const float* fea   = (const float*)d_in[1];   // (4096, 512)
    const int*   label = (const int*)d_in[2];     // (4096,)
    float* out = (float*)d_out;

    char* ws = (char*)d_ws;
    short8* Bws      = (short8*)ws;               // 114688 B
    float* invf_tal  = (float*)(ws + 114688);     // 112 floats
    float* expos     = (float*)(ws + 115136);     // 100 floats
    float* gsum      = (float*)(ws + 115584);     // 112 floats
    int*   cnt       = (int*)  (ws + 116032);     // completion counter

    prep_all<<<28, 256, 0, stream>>>(attr, fea, label, Bws, invf_tal, expos, gsum, cnt);
    main_gemm<<<NBLK, 256, 0, stream>>>(attr, Bws, invf_tal, expos, gsum, cnt, out);
}

// Round 5
// 431.003 us; speedup vs baseline: 1.1127x; 1.1127x over previous
//
#include <hip/hip_runtime.h>
#include <hip/hip_bf16.h>

#define S_N   150000
#define DIM   512
#define NUSE  100
#define NPAD  112            // 7 tiles of 16
#define TALF  0.07f
#define BS    128            // s rows per block
#define NBLK  ((S_N + BS - 1) / BS)   // 1172; last block has 112 valid rows
#define NCHUNK (DIM / 32)    // 16

using short8 = __attribute__((ext_vector_type(8))) short;
using f32x4  = __attribute__((ext_vector_type(4))) float;

__device__ __forceinline__ short f2bf(float f) {
    union { float f; unsigned u; } x; x.f = f;
    unsigned r = x.u + 0x7FFF + ((x.u >> 16) & 1);   // RNE
    return (short)(r >> 16);
}

// ---- P1: pack fea (first 112 rows) into B-fragment order + zero gsum ----
__global__ void prep_b(const float* __restrict__ fea, short8* __restrict__ Bws,
                       float* __restrict__ gsum) {
    int idx = blockIdx.x * 256 + threadIdx.x;        // 0..7167 exactly (28 blocks)
    if (blockIdx.x == 0 && threadIdx.x < NPAD) gsum[threadIdx.x] = 0.f;
    int c    = idx / 448;
    int r    = idx % 448;
    int tn   = r / 64;
    int lane = r % 64;
    int n     = tn * 16 + (lane & 15);
    int dbase = c * 32 + ((lane >> 4) & 3) * 8;
    const float* fp = fea + n * DIM + dbase;
    short8 o;
#pragma unroll
    for (int j = 0; j < 8; ++j) o[j] = f2bf(fp[j]);
    Bws[idx] = o;
}

// ---- P2: fea norms (1/(TAL*||f||)) for n<112, fp32 positive logits for n<100 ----
__global__ void prep_norm_pos(const float* __restrict__ attr, const float* __restrict__ fea,
                              const int* __restrict__ label,
                              float* __restrict__ invf_tal, float* __restrict__ expos) {
    int wv   = blockIdx.x * 4 + (threadIdx.x >> 6);  // one wave per n
    int lane = threadIdx.x & 63;
    if (wv >= NPAD) return;
    const float* f = fea + wv * DIM;
    float ss = 0.f;
#pragma unroll
    for (int j = 0; j < 8; ++j) { float v = f[lane * 8 + j]; ss += v * v; }
    for (int o = 1; o < 64; o <<= 1) ss += __shfl_xor(ss, o);
    if (lane == 0) invf_tal[wv] = rsqrtf(ss) * (1.0f / TALF);
    if (wv < NUSE) {
        int lab = label[wv];
        float dt = 0.f, aq = 0.f;
#pragma unroll
        for (int j = 0; j < 8; ++j) {
            int d = j * 64 + lane;
            float a  = attr[(size_t)d * S_N + lab];
            float fe = f[d];
            dt += a * fe; aq += a * a;
        }
        for (int o = 1; o < 64; o <<= 1) { dt += __shfl_xor(dt, o); aq += __shfl_xor(aq, o); }
        if (lane == 0) expos[wv] = dt * rsqrtf(aq) * rsqrtf(ss) * (1.0f / TALF);
    }
}

// ---- Main: stream attr once, MFMA vs packed fea, fused norm + exp partial sums ----
// FULL=true: all 128 rows valid (blocks 0..NBLK-2). FULL=false: tail block, 112 rows.
template<bool FULL>
__device__ __forceinline__ void gemm_body(const float* __restrict__ A,
                                          const short8* __restrict__ Bws,
                                          const float* __restrict__ invf_tal,
                                          float* __restrict__ gsum,
                                          float psum[4][NPAD]) {
    const int tid  = threadIdx.x;
    const int w    = tid >> 6, lane = tid & 63;
    const int q    = lane >> 4, l16 = lane & 15;
    const int s0   = blockIdx.x * BS;
    const int srow0 = s0 + w * 32 + l16;             // A-frag row, mt=0 (mt=1: +16)
    const bool v0 = FULL || (srow0 < S_N);
    const bool v1 = FULL || (srow0 + 16 < S_N);

    const float* a0 = A + (size_t)(q * 8) * S_N + srow0;  // k = c*32 + q*8 + j

    f32x4 acc[2][7];
#pragma unroll
    for (int mt = 0; mt < 2; ++mt)
#pragma unroll
        for (int tn = 0; tn < 7; ++tn) acc[mt][tn] = f32x4{0.f, 0.f, 0.f, 0.f};

    float ss0 = 0.f, ss1 = 0.f;       // fp32 column sumsq (this lane's k-subset)
    float raw0[8], raw1[8];
#pragma unroll
    for (int j = 0; j < 8; ++j) {     // prefetch chunk 0
        raw0[j] = v0 ? a0[(size_t)j * S_N] : 0.f;
        raw1[j] = v1 ? a0[(size_t)j * S_N + 16] : 0.f;
    }
    const short8* bp = Bws + lane;

    for (int c = 0; c < NCHUNK; ++c) {
        short8 bfr[7];
#pragma unroll
        for (int tn = 0; tn < 7; ++tn) bfr[tn] = bp[(c * 7 + tn) * 64];
        short8 af0, af1;
#pragma unroll
        for (int j = 0; j < 8; ++j) {
            float x0 = raw0[j], x1 = raw1[j];
            ss0 += x0 * x0; ss1 += x1 * x1;
            af0[j] = f2bf(x0); af1[j] = f2bf(x1);
        }
        if (c + 1 < NCHUNK) {         // prefetch next chunk's A while MFMAs run
            const float* an = a0 + (size_t)(c + 1) * 32 * S_N;
#pragma unroll
            for (int j = 0; j < 8; ++j) {
                raw0[j] = v0 ? an[(size_t)j * S_N] : 0.f;
                raw1[j] = v1 ? an[(size_t)j * S_N + 16] : 0.f;
            }
        }
#pragma unroll
        for (int tn = 0; tn < 7; ++tn) {
            acc[0][tn] = __builtin_amdgcn_mfma_f32_16x16x32_bf16(af0, bfr[tn], acc[0][tn], 0, 0, 0);
            acc[1][tn] = __builtin_amdgcn_mfma_f32_16x16x32_bf16(af1, bfr[tn], acc[1][tn], 0, 0, 0);
        }
    }

    // full column sumsq: rows are shared across the 4 quads
    ss0 += __shfl_xor(ss0, 16); ss0 += __shfl_xor(ss0, 32);
    ss1 += __shfl_xor(ss1, 16); ss1 += __shfl_xor(ss1, 32);
    float inva0 = v0 ? rsqrtf(ss0) : 0.f;   // belongs to row l16 / l16+16
    float inva1 = v1 ? rsqrtf(ss1) : 0.f;
    // redistribute to C-layout rows (row = q*4 + reg): lane (q*4+reg) holds that row's value
    float ir0[4], ir1[4];
#pragma unroll
    for (int reg = 0; reg < 4; ++reg) {
        ir0[reg] = __shfl(inva0, q * 4 + reg);
        ir1[reg] = __shfl(inva1, q * 4 + reg);
    }
    float invf_l[7];
#pragma unroll
    for (int tn = 0; tn < 7; ++tn) invf_l[tn] = invf_tal[tn * 16 + l16];

    const float M = 1.0f / TALF;
    const int rowbase = s0 + w * 32 + q * 4;
#pragma unroll
    for (int tn = 0; tn < 7; ++tn) {
        float sacc = 0.f;
#pragma unroll
        for (int reg = 0; reg < 4; ++reg) {
            bool rv0 = FULL || ((rowbase + reg) < S_N);
            bool rv1 = FULL || ((rowbase + 16 + reg) < S_N);
            float ex0 = acc[0][tn][reg] * ir0[reg] * invf_l[tn];
            float ex1 = acc[1][tn][reg] * ir1[reg] * invf_l[tn];
            sacc += rv0 ? __expf(ex0 - M) : 0.f;
            sacc += rv1 ? __expf(ex1 - M) : 0.f;
        }
        sacc += __shfl_xor(sacc, 16);
        sacc += __shfl_xor(sacc, 32);
        if (lane < 16) psum[w][tn * 16 + lane] = sacc;
    }
    __syncthreads();
    if (tid < NPAD) {
        float t = psum[0][tid] + psum[1][tid] + psum[2][tid] + psum[3][tid];
        atomicAdd(&gsum[tid], t);
    }
}

// block=256, launch_bounds(256,2). Measured map (dur_us): scalar(256,3)=435.5,
// scalar(256,2)=431.4 (best), LDS-dbuf(256,3)=437.4, fused-finalize=479.6
// (device-scope fence/L2-maintenance x1172 blocks + L2 B-evictions). Do not fuse
// grid-wide finalize into this kernel; keep separate tiny finalize launch.
__global__ __launch_bounds__(256, 2)
void main_gemm(const float* __restrict__ A, const short8* __restrict__ Bws,
               const float* __restrict__ invf_tal, float* __restrict__ gsum) {
    __shared__ float psum[4][NPAD];
    if (blockIdx.x != NBLK - 1) {
        gemm_body<true>(A, Bws, invf_tal, gsum, psum);
    } else {
        gemm_body<false>(A, Bws, invf_tal, gsum, psum);
    }
}

// ---- Final: loss = mean_n (M + log(sumexp[n]) - expos[n]) ----
__global__ void finalize(const float* __restrict__ gsum, const float* __restrict__ expos,
                         float* __restrict__ out) {
    __shared__ float r[128];
    int tid = threadIdx.x;
    const float M = 1.0f / TALF;
    float v = 0.f;
    if (tid < NUSE) v = (M + logf(gsum[tid])) - expos[tid];
    r[tid] = v;
    __syncthreads();
    for (int s = 64; s > 0; s >>= 1) {
        if (tid < s) r[tid] += r[tid + s];
        __syncthreads();
    }
    if (tid == 0) out[0] = r[0] * (1.0f / NUSE);
}

extern "C" void kernel_launch(void* const* d_in, const int* in_sizes, int n_in,
                              void* d_out, int out_size, void* d_ws, size_t ws_size,
                              hipStream_t stream) {
    const float* attr  = (const float*)d_in[0];   // (512, 150000)
    const float* fea   = (const float*)d_in[1];   // (4096, 512)
    const int*   label = (const int*)d_in[2];     // (4096,)
    float* out = (float*)d_out;

    char* ws = (char*)d_ws;
    short8* Bws      = (short8*)ws;               // 114688 B
    float* invf_tal  = (float*)(ws + 114688);     // 112 floats
    float* expos     = (float*)(ws + 115136);     // 100 floats
    float* gsum      = (float*)(ws + 115584);     // 112 floats

    prep_b<<<28, 256, 0, stream>>>(fea, Bws, gsum);
    prep_norm_pos<<<28, 256, 0, stream>>>(attr, fea, label, invf_tal, expos);
    main_gemm<<<NBLK, 256, 0, stream>>>(attr, Bws, invf_tal, gsum);
    finalize<<<1, 128, 0, stream>>>(gsum, expos, out);
}